// Round 6
// baseline (327.056 us; speedup 1.0000x reference)
//
#include <hip/hip_runtime.h>
#include <hip/hip_bf16.h>

typedef __bf16 bf16;
typedef __bf16 bf16x8 __attribute__((ext_vector_type(8)));
typedef float f32x4 __attribute__((ext_vector_type(4)));
typedef float f32x16 __attribute__((ext_vector_type(16)));
typedef unsigned u32x4 __attribute__((ext_vector_type(4)));

#define MFMA16(a, b, c) __builtin_amdgcn_mfma_f32_16x16x32_bf16((a), (b), (c), 0, 0, 0)
#define MFMA32(a, b, c) __builtin_amdgcn_mfma_f32_32x32x16_bf16((a), (b), (c), 0, 0, 0)

// XCD-chunked block swizzle (nblk % 8 == 0): each XCD gets a contiguous chunk.
__device__ __forceinline__ int xcd_swizzle(int bid, int nblk) {
  const int per = nblk >> 3;
  return (bid & 7) * per + (bid >> 3);
}

__device__ __forceinline__ void gload_lds16(const bf16* g, bf16* lds) {
  __builtin_amdgcn_global_load_lds(
      (const __attribute__((address_space(1))) void*)g,
      (__attribute__((address_space(3))) void*)lds, 16, 0, 0);
}

__device__ __forceinline__ unsigned pack2bf(float a, float b) {
  const unsigned short ua = __builtin_bit_cast(unsigned short, (bf16)a);
  const unsigned short ub = __builtin_bit_cast(unsigned short, (bf16)b);
  return (unsigned)ua | ((unsigned)ub << 16);
}

// ---------------- GEMM: C[M,N] = (A[M,K] @ W[N,K]^T + bias) * cscale --------
// (unchanged — 4 GEMMs + transpose measured ~88us)
template <typename T> struct StageRegs;
template <> struct StageRegs<float> { float4 lo[4], hi[4]; };
template <> struct StageRegs<bf16> { bf16x8 v[4]; };

template <typename T>
__device__ __forceinline__ void stage_issue(StageRegs<T>& r, const T* base,
                                            int rowstride, int brc, int k0,
                                            int tid) {
#pragma unroll
  for (int i = 0; i < 4; ++i) {
    const int c = i * 256 + tid;
    const int row = c >> 3, lin = c & 7;
    const T* p = base + (size_t)(brc + row) * rowstride + k0 + lin * 8;
    if constexpr (sizeof(T) == 4) {
      r.lo[i] = *reinterpret_cast<const float4*>(p);
      r.hi[i] = *reinterpret_cast<const float4*>(p + 4);
    } else {
      r.v[i] = *reinterpret_cast<const bf16x8*>(p);
    }
  }
}

template <typename T>
__device__ __forceinline__ void stage_write(const StageRegs<T>& r, bf16* sm,
                                            int tid) {
#pragma unroll
  for (int i = 0; i < 4; ++i) {
    const int c = i * 256 + tid;
    const int row = c >> 3, lin = c & 7;
    const int slot = lin ^ (row & 7);
    bf16x8 v;
    if constexpr (sizeof(T) == 4) {
      const float4 a = r.lo[i], b = r.hi[i];
      v[0] = (bf16)a.x; v[1] = (bf16)a.y; v[2] = (bf16)a.z; v[3] = (bf16)a.w;
      v[4] = (bf16)b.x; v[5] = (bf16)b.y; v[6] = (bf16)b.z; v[7] = (bf16)b.w;
    } else {
      v = r.v[i];
    }
    *reinterpret_cast<bf16x8*>(sm + row * 64 + slot * 8) = v;
  }
}

template <typename TA, typename TB, typename TC>
__global__ __launch_bounds__(256, 2) void gemm_bias_kernel(
    const TA* __restrict__ A, const TB* __restrict__ W,
    const float* __restrict__ bias, TC* __restrict__ C, int M, int N, int K,
    int nbc, float cscale) {
  __shared__ bf16 Asm[2][128 * 64];
  __shared__ bf16 Bsm[2][128 * 64];
  const int tid = threadIdx.x;
  const int lane = tid & 63;
  const int wid = tid >> 6;
  const int l15 = lane & 15;
  const int l4 = lane >> 4;
  const int bid = xcd_swizzle(blockIdx.x, gridDim.x);
  const int brow = (bid / nbc) << 7;
  const int bcol = (bid % nbc) << 7;
  const int wm = (wid >> 1) << 6;
  const int wn = (wid & 1) << 6;

  f32x4 acc[4][4] = {};

  StageRegs<TA> ra;
  StageRegs<TB> rb;
  stage_issue(ra, A, K, brow, 0, tid);
  stage_issue(rb, W, K, bcol, 0, tid);

  const int nt = K >> 6;
  int p = 0;
  for (int t = 0; t < nt; ++t) {
    stage_write(ra, Asm[p], tid);
    stage_write(rb, Bsm[p], tid);
    if (t + 1 < nt) {
      stage_issue(ra, A, K, brow, (t + 1) << 6, tid);
      stage_issue(rb, W, K, bcol, (t + 1) << 6, tid);
    }
    __syncthreads();
#pragma unroll
    for (int kk = 0; kk < 2; ++kk) {
      bf16x8 af[4], bfr[4];
#pragma unroll
      for (int m = 0; m < 4; ++m) {
        const int row = wm + m * 16 + l15;
        const int slot = (kk * 4 + l4) ^ (row & 7);
        af[m] = *reinterpret_cast<const bf16x8*>(Asm[p] + row * 64 + slot * 8);
      }
#pragma unroll
      for (int n = 0; n < 4; ++n) {
        const int row = wn + n * 16 + l15;
        const int slot = (kk * 4 + l4) ^ (row & 7);
        bfr[n] = *reinterpret_cast<const bf16x8*>(Bsm[p] + row * 64 + slot * 8);
      }
      __builtin_amdgcn_s_setprio(1);
#pragma unroll
      for (int m = 0; m < 4; ++m)
#pragma unroll
        for (int n = 0; n < 4; ++n)
          acc[m][n] = MFMA16(af[m], bfr[n], acc[m][n]);
      __builtin_amdgcn_s_setprio(0);
    }
    p ^= 1;
  }

  const int r0 = brow + wm + l4 * 4;
  const int c0 = bcol + wn + l15;
#pragma unroll
  for (int n = 0; n < 4; ++n) {
    const float bv = bias[c0 + n * 16];
#pragma unroll
    for (int m = 0; m < 4; ++m) {
#pragma unroll
      for (int r = 0; r < 4; ++r) {
        C[(size_t)(r0 + m * 16 + r) * N + (c0 + n * 16)] =
            (TC)((acc[m][n][r] + bv) * cscale);
      }
    }
  }
}

// Vt[(b*16+h)*64 + d][s] = V[(b*2048+s)*1024 + h*64 + d]   (bf16 -> bf16)
__global__ __launch_bounds__(256) void transpose_v_kernel(
    const bf16* __restrict__ V, bf16* __restrict__ Vt) {
  __shared__ unsigned short t[64][72];
  const int bid = blockIdx.x;
  const int st = bid & 31;
  const int h = (bid >> 5) & 15;
  const int b = bid >> 9;
  const int s0 = st * 64;
  const int tid = threadIdx.x;
#pragma unroll
  for (int i = 0; i < 2; ++i) {
    const int c = i * 256 + tid;
    const int row = c >> 3;
    const int off = (c & 7) * 8;
    const uint4 v = *reinterpret_cast<const uint4*>(
        &V[(size_t)(b * 2048 + s0 + row) * 1024 + h * 64 + off]);
    *reinterpret_cast<uint4*>(&t[row][off]) = v;
  }
  __syncthreads();
#pragma unroll
  for (int i = 0; i < 2; ++i) {
    const int c = i * 256 + tid;
    const int d = c >> 3;
    const int so = (c & 7) * 8;
    unsigned short tmp[8] __attribute__((aligned(16)));
#pragma unroll
    for (int j = 0; j < 8; ++j) tmp[j] = t[so + j][d];
    *reinterpret_cast<uint4*>(
        &Vt[(size_t)((b * 16 + h) * 64 + d) * 2048 + s0 + so]) =
        *reinterpret_cast<const uint4*>(tmp);
  }
}

// ---------------- Flash attention: 32x32 MFMA, in-register P ---------------
// Block = (b, h, 128 q-rows); 4 waves x 32 q-rows. K/Vt tiles (64 k x 64 d)
// LDS-staged double-buffered. S^T = MFMA32(K,Q): lane q=l&31 (2 copies l^32)
// holds 32 of 64 k-values -> softmax reductions are 1 shfl each. P stays in
// registers: pack to bf16 pairs, exchange halves with lane^32 (8 shfl_xor),
// assemble PV A-frags directly. Defer-max (T13): o-rescale only when a row's
// max grows >8; alpha/lrow redistributed to o rows via bpermute then only.
__global__ __launch_bounds__(256, 2) void attn_kernel(
    const bf16* __restrict__ Q, const bf16* __restrict__ Kt,
    const bf16* __restrict__ Vt, const float* __restrict__ mask,
    bf16* __restrict__ ctx) {
  __shared__ bf16 Ksm[2][64 * 64];
  __shared__ bf16 Vsm[2][64 * 64];
  const int lid = xcd_swizzle(blockIdx.x, 1024);
  const int h = lid & 15;
  const int qb = (lid >> 4) & 15;
  const int b = lid >> 8;
  const int tid = threadIdx.x;
  const int lane = tid & 63;
  const int wid = tid >> 6;
  const int l31 = lane & 31;
  const int h5 = lane >> 5;

  const int qbase = qb * 128 + wid * 32;

  // Q B-frags: qf[c] = Q[qbase+l31][16c + 8*h5 + j], j=0..7 (Q pre-scaled 1/8)
  bf16x8 qf[4];
#pragma unroll
  for (int c = 0; c < 4; ++c)
    qf[c] = *reinterpret_cast<const bf16x8*>(
        &Q[(size_t)(b * 2048 + qbase + l31) * 1024 + h * 64 + c * 16 + h5 * 8]);

  // o[dsub]: D layout rows q=(reg&3)+8*(reg>>2)+4*h5, col d=dsub*32+l31
  f32x16 o[2] = {};
  float mrow = -1e30f, lrow = 0.f;  // softmax state for row q = l31 (2 copies)

  const float LOG2E = 1.44269504088896f;
  const bf16* Kb = Kt + (size_t)b * 2048 * 1024 + h * 64;
  const bf16* Vb = Vt + (size_t)(b * 16 + h) * 64 * 2048;
  const float* Mb = mask + (size_t)b * 2048 * 2048;

  f32x4 mreg[2][4];  // mask[qbase+l31][k0 + 32s + 8g + 4*h5 + r]

  auto stage = [&](int p, int k0) {
#pragma unroll
    for (int i = 0; i < 2; ++i) {
      const int c = i * 256 + tid;
      const int row = c >> 3;
      const int lin = (c & 7) ^ (row & 7);
      gload_lds16(Kb + (size_t)(k0 + row) * 1024 + lin * 8, &Ksm[p][c * 8]);
      gload_lds16(Vb + (size_t)row * 2048 + k0 + lin * 8, &Vsm[p][c * 8]);
    }
  };
  auto load_mask = [&](int k0) {
#pragma unroll
    for (int s = 0; s < 2; ++s)
#pragma unroll
      for (int g = 0; g < 4; ++g)
        mreg[s][g] = *reinterpret_cast<const f32x4*>(
            &Mb[(size_t)(qbase + l31) * 2048 + k0 + s * 32 + g * 8 + h5 * 4]);
  };

  stage(0, 0);
  load_mask(0);
  asm volatile("s_waitcnt vmcnt(0)" ::: "memory");
  __syncthreads();

  int p = 0;
  for (int t = 0; t < 32; ++t) {
    const int k0 = t << 6;
    if (t + 1 < 32) stage(p ^ 1, k0 + 64);  // in flight during compute

    // S^T: sf[s] holds S[k = 32s + (reg&3)+8*(reg>>2)+4*h5][q = l31]
    f32x16 sf[2] = {};
    __builtin_amdgcn_s_setprio(1);
#pragma unroll
    for (int s = 0; s < 2; ++s) {
#pragma unroll
      for (int c = 0; c < 4; ++c) {
        const int row = s * 32 + l31;
        const int slot = (2 * c + h5) ^ (row & 7);
        const bf16x8 kf =
            *reinterpret_cast<const bf16x8*>(&Ksm[p][row * 64 + slot * 8]);
        sf[s] = MFMA32(kf, qf[c], sf[s]);
      }
    }
    __builtin_amdgcn_s_setprio(0);

    // mask add + this lane's partial row max (32 of 64 k-values of row l31)
    float rmax = -1e30f;
#pragma unroll
    for (int s = 0; s < 2; ++s) {
#pragma unroll
      for (int reg = 0; reg < 16; ++reg) {
        const float x = sf[s][reg] + mreg[s][reg >> 2][reg & 3];
        sf[s][reg] = x;
        rmax = fmaxf(rmax, x);
      }
    }
    if (t + 1 < 32) load_mask(k0 + 64);  // prefetch next mask

    rmax = fmaxf(rmax, __shfl_xor(rmax, 32, 64));  // partner holds other 32

    // defer-max: rescale only if some row's max grew by >8
    if (!__all(rmax <= mrow + 8.0f)) {
      const float mn = fmaxf(mrow, rmax);
      const float alpha = __builtin_exp2f((mrow - mn) * LOG2E);
      mrow = mn;
      lrow *= alpha;
#pragma unroll
      for (int reg = 0; reg < 16; ++reg) {
        const int qr = (reg & 3) + 8 * (reg >> 2) + 4 * h5;
        const float a = __shfl(alpha, qr, 64);
        o[0][reg] *= a;
        o[1][reg] *= a;
      }
    }

    // P = exp2(S*log2e - m*log2e) -> bf16 pairs in regs
    const float negmL = -mrow * LOG2E;
    float rsum = 0.f;
    unsigned pk[2][4][2];  // [s][g][half]: p(r=2*half), p(r=2*half+1)
#pragma unroll
    for (int s = 0; s < 2; ++s) {
#pragma unroll
      for (int g = 0; g < 4; ++g) {
        float pv[4];
#pragma unroll
        for (int r = 0; r < 4; ++r) {
          pv[r] = __builtin_exp2f(
              __builtin_fmaf(sf[s][g * 4 + r], LOG2E, negmL));
          rsum += pv[r];
        }
        pk[s][g][0] = pack2bf(pv[0], pv[1]);
        pk[s][g][1] = pack2bf(pv[2], pv[3]);
      }
    }
    rsum += __shfl_xor(rsum, 32, 64);
    lrow += rsum;

    // PV: per kc-chunk c, build A-frag P[q][16c + 8*h5 + j] by exchanging
    // bf16-pair u32s with partner lane l^32, then 2 MFMA32 (dsub 0,1).
#pragma unroll
    for (int c = 0; c < 4; ++c) {
      const int s = c >> 1;
      const int ge = (2 * c) & 3;       // index needed by h5=0 targets
      const int go = (2 * c + 1) & 3;   // index needed by h5=1 targets
      const unsigned send0 = h5 ? pk[s][ge][0] : pk[s][go][0];
      const unsigned send1 = h5 ? pk[s][ge][1] : pk[s][go][1];
      const unsigned recv0 = __shfl_xor(send0, 32, 64);
      const unsigned recv1 = __shfl_xor(send1, 32, 64);
      const unsigned own0 = h5 ? pk[s][go][0] : pk[s][ge][0];
      const unsigned own1 = h5 ? pk[s][go][1] : pk[s][ge][1];
      const u32x4 uu = {h5 ? recv0 : own0, h5 ? recv1 : own1,
                        h5 ? own0 : recv0, h5 ? own1 : recv1};
      const bf16x8 pa = __builtin_bit_cast(bf16x8, uu);
      __builtin_amdgcn_s_setprio(1);
#pragma unroll
      for (int dsub = 0; dsub < 2; ++dsub) {
        const int row = dsub * 32 + l31;
        const int slot = (2 * c + h5) ^ (row & 7);
        const bf16x8 vf =
            *reinterpret_cast<const bf16x8*>(&Vsm[p][row * 64 + slot * 8]);
        o[dsub] = MFMA32(pa, vf, o[dsub]);
      }
      __builtin_amdgcn_s_setprio(0);
    }

    asm volatile("s_waitcnt vmcnt(0)" ::: "memory");
    __syncthreads();
    p ^= 1;
  }

  // ctx = O / l : lrow lives at lanes l31==q; redistribute to o rows.
  const float linv = __builtin_amdgcn_rcpf(lrow);
#pragma unroll
  for (int reg = 0; reg < 16; ++reg) {
    const int qr = (reg & 3) + 8 * (reg >> 2) + 4 * h5;
    const float li = __shfl(linv, qr, 64);
    const int q = qbase + qr;
#pragma unroll
    for (int dsub = 0; dsub < 2; ++dsub) {
      ctx[(size_t)(b * 2048 + q) * 1024 + h * 64 + dsub * 32 + l31] =
          (bf16)(o[dsub][reg] * li);
    }
  }
}

extern "C" void kernel_launch(void* const* d_in, const int* in_sizes, int n_in,
                              void* d_out, int out_size, void* d_ws,
                              size_t ws_size, hipStream_t stream) {
  const float* key = (const float*)d_in[0];
  const float* query = (const float*)d_in[1];
  const float* value = (const float*)d_in[2];
  const float* mask = (const float*)d_in[3];
  const float* wq = (const float*)d_in[4];
  const float* bq = (const float*)d_in[5];
  const float* wk = (const float*)d_in[6];
  const float* bk = (const float*)d_in[7];
  const float* wv = (const float*)d_in[8];
  const float* bv = (const float*)d_in[9];
  const float* wo = (const float*)d_in[10];
  const float* bo = (const float*)d_in[11];
  float* out = (float*)d_out;

  const size_t NBSH = (size_t)4 * 2048 * 1024;
  bf16* Qws = (bf16*)d_ws;   // Q (pre-scaled by 1/8), later ctx in place
  bf16* Kws = Qws + NBSH;
  bf16* Vt = Kws + NBSH;     // total ws use: 50.3 MB
  bf16* Vtmp = (bf16*)d_out; // stage bf16 V projection in d_out

  const dim3 blk(256);
  gemm_bias_kernel<float, float, bf16><<<512, blk, 0, stream>>>(
      query, wq, bq, Qws, 8192, 1024, 1024, 8, 0.125f);
  gemm_bias_kernel<float, float, bf16><<<512, blk, 0, stream>>>(
      key, wk, bk, Kws, 8192, 1024, 1024, 8, 1.0f);
  gemm_bias_kernel<float, float, bf16><<<512, blk, 0, stream>>>(
      value, wv, bv, Vtmp, 8192, 1024, 1024, 8, 1.0f);
  transpose_v_kernel<<<2048, blk, 0, stream>>>(Vtmp, Vt);
  attn_kernel<<<1024, blk, 0, stream>>>(Qws, Kws, Vt, mask, Qws);
  gemm_bias_kernel<bf16, float, float><<<512, blk, 0, stream>>>(
      Qws, wo, bo, out, 8192, 1024, 1024, 8, 1.0f);
}